// Round 10
// baseline (140.899 us; speedup 1.0000x reference)
//
#include <hip/hip_runtime.h>
#include <hip/hip_bf16.h>

// Problem constants
#define BB 2
#define FDIM 2048
#define FH 64
#define FW 128
#define NPIX (FH*FW)        // 8192 pixels per (dom,b)
#define NC 19
#define SH 512
#define SW 1024

#define KS 4                // pixel splits per (d,b) plane
#define PXS (NPIX/KS)       // 2048 pixels per block (512 per wave)

// Workspace layout (bytes). Only psq+cnt are zeroed (1.4 KB); sump is
// written exactly once per location (no atomics, no zeroing).
#define OFF_PSQ   0                         // float psq[8][2][19]      = 1216 B
#define OFF_CNT   1216                      // uint  cnt[2][19]         = 152 B
#define ZERO_BYTES 1408
#define OFF_SUMP  1408                      // float sump[8][2][19][2048] = 2490368 B
#define OFF_LAB   2491776                   // uchar labels[2][2][8192] = 32768 B
#define OFF_CENT  2524544                   // float cent[19][2048]     = 155648 B
#define OFF_DOTS  2680192                   // float dots[57]
#define OFF_ROW   2680420                   // float row[19]

typedef __attribute__((ext_vector_type(8))) short short8v;   // 8 bf16 (4 VGPRs)
typedef __attribute__((ext_vector_type(4))) float f32x4;     // MFMA C/D
typedef __attribute__((ext_vector_type(4))) float f4v;       // NT-loadable float4

__device__ inline short f32_to_bf16_bits(float x) {
  __hip_bfloat16 h = __float2bfloat16(x);
  return *reinterpret_cast<short*>(&h);
}
__device__ inline float bf16_bits_to_f32(short s) {
  unsigned u = ((unsigned)s & 0xFFFFu) << 16;
  return __uint_as_float(u);
}

// ---------------------------------------------------------------------------
// Kernel 1: labels via align_corners bilinear downsample + argmax over C.
// 4 lanes per output pixel, shfl_xor argmax merge, first-max tie-break.
// Replicates jnp.linspace f32 arithmetic / mul-add association exactly.
// ---------------------------------------------------------------------------
__global__ __launch_bounds__(256) void labels_kernel(
    const float* __restrict__ sm_s, const float* __restrict__ sm_t,
    unsigned char* __restrict__ labels, unsigned int* __restrict__ cnt) {
  __shared__ unsigned int lcnt[NC];
  int tid = threadIdx.x;
  if (tid < NC) lcnt[tid] = 0u;
  __syncthreads();

  int g = blockIdx.x * 256 + tid;          // 0..131071
  int pixid = g >> 2;                      // 0..32767
  int sub = g & 3;
  int dom = pixid >> 14;                   // block-uniform
  int rem = pixid & 16383;
  int b   = rem >> 13;
  int pix = rem & (NPIX - 1);
  int oy  = pix >> 7;
  int ox  = pix & (FW - 1);

  const float* sm = dom ? sm_t : sm_s;

  const float step_y = 511.0f / 63.0f;
  const float step_x = 1023.0f / 127.0f;
  float fy = __fmul_rn((float)oy, step_y);
  float fx = __fmul_rn((float)ox, step_x);
  int y0 = (int)floorf(fy); int y1 = min(y0 + 1, SH - 1);
  int x0 = (int)floorf(fx); int x1 = min(x0 + 1, SW - 1);
  float wy = __fsub_rn(fy, (float)y0);
  float wx = __fsub_rn(fx, (float)x0);
  float omwy = __fsub_rn(1.0f, wy);
  float omwx = __fsub_rn(1.0f, wx);

  const float* base = sm + (size_t)b * (NC * SH * SW);
  float best = -1.0f; int bestc = 127;
  for (int c = sub; c < NC; c += 4) {
    const float* p = base + (size_t)c * (SH * SW);
    float v00 = p[y0 * SW + x0];
    float v01 = p[y0 * SW + x1];
    float v10 = p[y1 * SW + x0];
    float v11 = p[y1 * SW + x1];
    float r0  = __fadd_rn(__fmul_rn(v00, omwy), __fmul_rn(v10, wy));
    float r1  = __fadd_rn(__fmul_rn(v01, omwy), __fmul_rn(v11, wy));
    float val = __fadd_rn(__fmul_rn(r0, omwx), __fmul_rn(r1, wx));
    if (val > best) { best = val; bestc = c; }
  }
#pragma unroll
  for (int off = 1; off <= 2; off <<= 1) {
    float ov = __shfl_xor(best, off, 64);
    int   oc = __shfl_xor(bestc, off, 64);
    if (ov > best || (ov == best && oc < bestc)) { best = ov; bestc = oc; }
  }
  if (sub == 0) {
    labels[pixid] = (unsigned char)bestc;
    atomicAdd(&lcnt[bestc], 1u);
  }
  __syncthreads();
  if (tid < NC) atomicAdd(&cnt[dom * NC + tid], lcnt[tid]);
}

// ---------------------------------------------------------------------------
// Kernel 2 (hot): segment-sum as MFMA matmul, wave-private pipelines.
// R10 changes vs R9:
//  - 2-deep register prefetch (ld0/ld1): loads issued 2 compute-windows
//    before their vmcnt wait (~1200cyc cover vs ~900cyc HBM latency).
//  - outputs to PRIVATE slice sump[hi][d][c][fslice] with plain stores:
//    no global atomics, no zeroed accumulator (kills the 305KB fill AND
//    the 31MB atomic write-bounce). centroid_kernel folds the 8 partials.
// NT feature loads kept (zero-reuse stream; R9: 103->77us).
// ---------------------------------------------------------------------------
__global__ __launch_bounds__(256, 8) void segsum_kernel(
    const float* __restrict__ feat_s, const float* __restrict__ feat_t,
    const unsigned char* __restrict__ labels,
    float* __restrict__ sump, float* __restrict__ psq) {
  __shared__ unsigned short Abuf[4][2][16][64];   // 4 waves x dbuf x 2KB = 16KB

  int tid = threadIdx.x;
  int wv = tid >> 6, l = tid & 63;
  int m16 = l & 15, grp = l >> 4;
  int lrow = l >> 4;                       // sub-row 0..3 for staging
  int lpx  = (l & 15) * 4;                 // px offset 0..60 for staging

  int low = blockIdx.x & 255;
  int hi  = blockIdx.x >> 8;               // 0..7 = (ks<<1)|b
  int d = low >> 7, strip = low & 127;
  int b = hi & 1, ks = hi >> 1;

  const float* feat = d ? feat_t : feat_s;
  int px0 = ks * PXS + wv * 512;           // wave-private 512-px chunk
  const float* fbase = feat + ((size_t)(b * FDIM + strip * 16)) * NPIX + px0;
  const unsigned char* labp = labels + (d * 2 + b) * NPIX + px0;

  unsigned short (*mybuf)[16][64] = Abuf[wv];    // [2][16][64]

  f32x4 accS0 = {0.f,0.f,0.f,0.f}, accS1 = {0.f,0.f,0.f,0.f};
  f32x4 accQ0 = {0.f,0.f,0.f,0.f}, accQ1 = {0.f,0.f,0.f,0.f};

  f4v ld0[4], ld1[4];

#define LOADW(REG, W)                                                         \
  _Pragma("unroll") for (int r = 0; r < 4; ++r)                               \
    REG[r] = __builtin_nontemporal_load(                                      \
        (const f4v*)(fbase + (size_t)(r * 4 + lrow) * NPIX + (W) * 64 + lpx));

#define WRITEW(REG, CUR)                                                      \
  _Pragma("unroll") for (int r = 0; r < 4; ++r) {                             \
    int row = r * 4 + lrow;                                                   \
    unsigned u0 = ((unsigned)(unsigned short)f32_to_bf16_bits(REG[r].x)) |    \
                  (((unsigned)(unsigned short)f32_to_bf16_bits(REG[r].y)) << 16);\
    unsigned u1 = ((unsigned)(unsigned short)f32_to_bf16_bits(REG[r].z)) |    \
                  (((unsigned)(unsigned short)f32_to_bf16_bits(REG[r].w)) << 16);\
    int wbyte = (row * 128 + lpx * 2) ^ ((row & 7) << 4);                     \
    *(uint2*)((char*)&mybuf[CUR][0][0] + wbyte) = make_uint2(u0, u1);         \
  }

#define COMPW(W, CUR)                                                         \
  _Pragma("unroll") for (int t = 0; t < 2; ++t) {                             \
    int rbyte = (m16 * 128 + t * 64 + grp * 16) ^ ((m16 & 7) << 4);           \
    short8v a = *(const short8v*)((const char*)&mybuf[CUR][0][0] + rbyte);    \
    short8v a2;                                                               \
    _Pragma("unroll") for (int j = 0; j < 8; ++j) {                           \
      float x = bf16_bits_to_f32(a[j]);                                       \
      a2[j] = f32_to_bf16_bits(x * x);                                        \
    }                                                                         \
    uint2 lw = *(const uint2*)(labp + (W) * 64 + t * 32 + grp * 8);           \
    short8v b0, b1;                                                           \
    _Pragma("unroll") for (int j = 0; j < 8; ++j) {                           \
      unsigned lab = ((j < 4 ? lw.x : lw.y) >> ((j & 3) * 8)) & 0xFFu;        \
      b0[j] = (lab == (unsigned)m16)        ? (short)0x3F80 : (short)0;       \
      b1[j] = (lab == (unsigned)(m16 + 16)) ? (short)0x3F80 : (short)0;       \
    }                                                                         \
    accS0 = __builtin_amdgcn_mfma_f32_16x16x32_bf16(a,  b0, accS0, 0, 0, 0);  \
    accS1 = __builtin_amdgcn_mfma_f32_16x16x32_bf16(a,  b1, accS1, 0, 0, 0);  \
    accQ0 = __builtin_amdgcn_mfma_f32_16x16x32_bf16(a2, b0, accQ0, 0, 0, 0);  \
    accQ1 = __builtin_amdgcn_mfma_f32_16x16x32_bf16(a2, b1, accQ1, 0, 0, 0);  \
  }

  // prologue: window 0 staged; window 1 in flight (ld0)
  LOADW(ld0, 0);
  WRITEW(ld0, 0);
  LOADW(ld0, 1);

#pragma unroll
  for (int w = 0; w < 8; w += 2) {
    if (w + 2 < 8) { LOADW(ld1, w + 2); }   // issue 2 windows ahead
    COMPW(w, 0);
    if (w + 1 < 8) { WRITEW(ld0, 1); }      // wait ld0 only (ld1 stays in flight)
    if (w + 3 < 8) { LOADW(ld0, w + 3); }
    COMPW(w + 1, 1);
    if (w + 2 < 8) { WRITEW(ld1, 0); }
  }
#undef LOADW
#undef WRITEW
#undef COMPW

  // ---- epilogue: barrier (Sred aliases Abuf), merge 4 waves, PRIVATE stores
  __syncthreads();
  float* Sred = (float*)&Abuf[0][0][0][0];   // [4][19][16] = 4864 B
  float* Qred = Sred + 4 * 19 * 16;          // [4][19]

  int c0 = l & 15, frb = (l >> 4) * 4;       // C/D: col=class, row=(l>>4)*4+reg
  *(f32x4*)&Sred[(wv * 19 + c0) * 16 + frb] = accS0;
  if (c0 < 3) *(f32x4*)&Sred[(wv * 19 + 16 + c0) * 16 + frb] = accS1;

  float q0 = accQ0[0] + accQ0[1] + accQ0[2] + accQ0[3];
  float q1 = accQ1[0] + accQ1[1] + accQ1[2] + accQ1[3];
  q0 += __shfl_xor(q0, 16, 64); q0 += __shfl_xor(q0, 32, 64);
  q1 += __shfl_xor(q1, 16, 64); q1 += __shfl_xor(q1, 32, 64);
  if (l < 16) Qred[wv * 19 + l] = q0;
  if (l < 3)  Qred[wv * 19 + 16 + l] = q1;
  __syncthreads();

  // block-private slice: sump[hi][d][c][strip*16+fr] — written exactly once
  float* myslice = sump + ((size_t)(hi * 2 + d) * NC) * FDIM + strip * 16;
  for (int t = tid; t < NC * 16; t += 256) {
    int c = t >> 4, fr = t & 15;
    float sv = Sred[(0 * 19 + c) * 16 + fr] + Sred[(1 * 19 + c) * 16 + fr] +
               Sred[(2 * 19 + c) * 16 + fr] + Sred[(3 * 19 + c) * 16 + fr];
    myslice[(size_t)c * FDIM + fr] = sv;
  }
  if (tid < NC) {
    float qv = Qred[tid] + Qred[19 + tid] + Qred[38 + tid] + Qred[57 + tid];
    unsafeAtomicAdd(&psq[(blockIdx.x & 7) * (2 * NC) + d * NC + tid], qv);
  }
}

// Block reduction helper (256 threads)
__device__ inline float block_reduce(float v, float* red, int tid) {
  red[tid] = v; __syncthreads();
  for (int s = 128; s > 0; s >>= 1) {
    if (tid < s) red[tid] += red[tid + s];
    __syncthreads();
  }
  float r = red[0];
  __syncthreads();
  return r;
}

// ---------------------------------------------------------------------------
// Kernel 3a: fold sump partials -> centroids + per-class dots.
// ---------------------------------------------------------------------------
__global__ __launch_bounds__(256) void centroid_kernel(
    const float* __restrict__ sump, const unsigned int* __restrict__ cnt,
    float* __restrict__ cent, float* __restrict__ dots) {
  __shared__ float red[256];
  int c = blockIdx.x;
  int tid = threadIdx.x;
  float cs = (float)cnt[c];
  float ct = (float)cnt[NC + c];
  float denom = fmaxf(cs + ct, 1.0f);
  float ds = 0.f, dt = 0.f, cc = 0.f;
  for (int f = tid; f < FDIM; f += 256) {
    float ssv = 0.f, stv = 0.f;
#pragma unroll
    for (int hi = 0; hi < 8; ++hi) {
      ssv += sump[((size_t)(hi * 2 + 0) * NC + c) * FDIM + f];
      stv += sump[((size_t)(hi * 2 + 1) * NC + c) * FDIM + f];
    }
    float cf = (ssv + stv) / denom;
    cent[(size_t)c * FDIM + f] = cf;
    ds += cf * ssv; dt += cf * stv; cc += cf * cf;
  }
  float rds = block_reduce(ds, red, tid);
  float rdt = block_reduce(dt, red, tid);
  float rcc = block_reduce(cc, red, tid);
  if (tid == 0) {
    dots[c] = rds;
    dots[NC + c] = rdt;
    dots[2 * NC + c] = rcc;
  }
}

// ---------------------------------------------------------------------------
// Kernel 3b: row[i] = sum_{j != i, seen i&j} sum_f (c_i - c_j)^2
// ---------------------------------------------------------------------------
__global__ __launch_bounds__(256) void pair_kernel(
    const float* __restrict__ cent, const unsigned int* __restrict__ cnt,
    float* __restrict__ row) {
  __shared__ float red[256];
  int i = blockIdx.x;
  int tid = threadIdx.x;
  bool seen_i = (cnt[i] + cnt[NC + i]) > 0u;
  float acc = 0.f;
  if (seen_i) {
    for (int j = 0; j < NC; ++j) {
      if (j == i) continue;
      if ((cnt[j] + cnt[NC + j]) == 0u) continue;
      for (int f = tid; f < FDIM; f += 256) {
        float dd = cent[(size_t)i * FDIM + f] - cent[(size_t)j * FDIM + f];
        acc += dd * dd;
      }
    }
  }
  float r = block_reduce(acc, red, tid);
  if (tid == 0) row[i] = r;
}

// ---------------------------------------------------------------------------
// Kernel 3c: fold psq partials, assemble the 3 outputs (p == 2).
// One wave, lane c handles class c; ballot/popc + shfl_down trees.
// ---------------------------------------------------------------------------
__global__ void final_kernel(
    const unsigned int* __restrict__ cnt, const float* __restrict__ psq,
    const float* __restrict__ dots, const float* __restrict__ row,
    float* __restrict__ out) {
  int l = threadIdx.x;                      // one wave of 64
  const float fdim = (float)FDIM;
  bool isC = l < NC;
  int c = isC ? l : 0;

  float cs = 0.f, ct = 0.f, qs = 0.f, qt = 0.f;
  float d_s = 0.f, d_t = 0.f, cc = 0.f, rw = 0.f;
  if (isC) {
    cs = (float)cnt[c]; ct = (float)cnt[NC + c];
#pragma unroll
    for (int x = 0; x < 8; ++x) {           // 16 independent loads, all in flight
      qs += psq[x * (2 * NC) + c];
      qt += psq[x * (2 * NC) + NC + c];
    }
    d_s = dots[c]; d_t = dots[NC + c]; cc = dots[2 * NC + c];
    rw = row[c];
  }
  bool seen = isC && (cs + ct > 0.f);
  float nseenf = (float)__popcll(__ballot(seen));
  float nvs    = (float)__popcll(__ballot(isC && cs > 0.f));
  float nvt    = (float)__popcll(__ballot(isC && ct > 0.f));

  float fs = 0.f, ft = 0.f, cd = 0.f;
  if (isC && cs > 0.f) {
    float ssq = fmaxf(qs - 2.0f * d_s + cs * cc, 0.f);
    fs = sqrtf(ssq) / (cs * fdim);
  }
  if (isC && ct > 0.f) {
    float ssq = fmaxf(qt - 2.0f * d_t + ct * cc, 0.f);
    ft = sqrtf(ssq) / (ct * fdim);
  }
  if (seen) cd = sqrtf(rw) / ((nseenf - 1.0f) * fdim);

#pragma unroll
  for (int off = 32; off > 0; off >>= 1) {
    fs += __shfl_down(fs, off, 64);
    ft += __shfl_down(ft, off, 64);
    cd += __shfl_down(cd, off, 64);
  }
  if (l == 0) {
    out[0] = cd / nseenf;
    out[1] = fs / nvs;
    out[2] = ft / nvt;
  }
}

extern "C" void kernel_launch(void* const* d_in, const int* in_sizes, int n_in,
                              void* d_out, int out_size, void* d_ws, size_t ws_size,
                              hipStream_t stream) {
  const float* sfeat = (const float*)d_in[0];
  const float* ssm   = (const float*)d_in[1];
  const float* tfeat = (const float*)d_in[2];
  const float* tsm   = (const float*)d_in[3];
  float* out = (float*)d_out;

  char* ws = (char*)d_ws;
  float*         psq    = (float*)(ws + OFF_PSQ);
  unsigned int*  cnt    = (unsigned int*)(ws + OFF_CNT);
  float*         sump   = (float*)(ws + OFF_SUMP);
  unsigned char* labels = (unsigned char*)(ws + OFF_LAB);
  float*         cent   = (float*)(ws + OFF_CENT);
  float*         dots   = (float*)(ws + OFF_DOTS);
  float*         row    = (float*)(ws + OFF_ROW);

  // zero only psq+cnt (1.4 KB; sump is written-once, needs no zeroing)
  hipMemsetAsync(ws, 0, ZERO_BYTES, stream);

  labels_kernel  <<<512,  256, 0, stream>>>(ssm, tsm, labels, cnt);
  segsum_kernel  <<<2048, 256, 0, stream>>>(sfeat, tfeat, labels, sump, psq);
  centroid_kernel<<<NC,   256, 0, stream>>>(sump, cnt, cent, dots);
  pair_kernel    <<<NC,   256, 0, stream>>>(cent, cnt, row);
  final_kernel   <<<1,    64,  0, stream>>>(cnt, psq, dots, row, out);
}

// Round 11
// 123.017 us; speedup vs baseline: 1.1454x; 1.1454x over previous
//
#include <hip/hip_runtime.h>
#include <hip/hip_bf16.h>

// Problem constants
#define BB 2
#define FDIM 2048
#define FH 64
#define FW 128
#define NPIX (FH*FW)        // 8192 pixels per (dom,b)
#define NC 19
#define SH 512
#define SW 1024

#define KS 4                // pixel splits per (d,b) plane
#define PXS (NPIX/KS)       // 2048 pixels per block (512 per wave)

// Workspace layout (bytes). EVERYTHING write-once: no memset, no atomics.
#define OFF_GCNT  0                         // uint  gcnt[512][19]      = 38912 B
#define OFF_SQP   38912                     // float sq_p[2048][19]     = 155648 B
#define OFF_SUMP  194560                    // float sump[16][19][2048] = 2490368 B
#define OFF_LAB   2684928                   // uchar labels[2][2][8192] = 32768 B
#define OFF_CENT  2717696                   // float cent[19][2048]     = 155648 B
#define OFF_DOTSP 2873344                   // float dotsp[8][19][3]    = 1824 B
#define OFF_PQP   2875168                   // float pqp[8][19][2]      = 1216 B
#define OFF_CNTF  2876384                   // float cntf[2][19]        = 152 B
#define OFF_ROW   2876536                   // float row[19]            = 76 B

typedef __attribute__((ext_vector_type(8))) short short8v;   // 8 bf16 (4 VGPRs)
typedef __attribute__((ext_vector_type(4))) float f32x4;     // MFMA C/D
typedef __attribute__((ext_vector_type(4))) float f4v;       // NT-loadable float4

__device__ inline short f32_to_bf16_bits(float x) {
  __hip_bfloat16 h = __float2bfloat16(x);
  return *reinterpret_cast<short*>(&h);
}
__device__ inline float bf16_bits_to_f32(short s) {
  unsigned u = ((unsigned)s & 0xFFFFu) << 16;
  return __uint_as_float(u);
}

// ---------------------------------------------------------------------------
// Kernel 1: labels via align_corners bilinear downsample + argmax over C.
// Per-block counts stored PLAIN to gcnt[bid][c] (no global atomics).
// ---------------------------------------------------------------------------
__global__ __launch_bounds__(256) void labels_kernel(
    const float* __restrict__ sm_s, const float* __restrict__ sm_t,
    unsigned char* __restrict__ labels, unsigned int* __restrict__ gcnt) {
  __shared__ unsigned int lcnt[NC];
  int tid = threadIdx.x;
  if (tid < NC) lcnt[tid] = 0u;
  __syncthreads();

  int g = blockIdx.x * 256 + tid;          // 0..131071
  int pixid = g >> 2;                      // 0..32767
  int sub = g & 3;
  int dom = pixid >> 14;                   // block-uniform (blocks 0..255 = dom0)
  int rem = pixid & 16383;
  int b   = rem >> 13;
  int pix = rem & (NPIX - 1);
  int oy  = pix >> 7;
  int ox  = pix & (FW - 1);

  const float* sm = dom ? sm_t : sm_s;

  const float step_y = 511.0f / 63.0f;
  const float step_x = 1023.0f / 127.0f;
  float fy = __fmul_rn((float)oy, step_y);
  float fx = __fmul_rn((float)ox, step_x);
  int y0 = (int)floorf(fy); int y1 = min(y0 + 1, SH - 1);
  int x0 = (int)floorf(fx); int x1 = min(x0 + 1, SW - 1);
  float wy = __fsub_rn(fy, (float)y0);
  float wx = __fsub_rn(fx, (float)x0);
  float omwy = __fsub_rn(1.0f, wy);
  float omwx = __fsub_rn(1.0f, wx);

  const float* base = sm + (size_t)b * (NC * SH * SW);
  float best = -1.0f; int bestc = 127;
  for (int c = sub; c < NC; c += 4) {
    const float* p = base + (size_t)c * (SH * SW);
    float v00 = p[y0 * SW + x0];
    float v01 = p[y0 * SW + x1];
    float v10 = p[y1 * SW + x0];
    float v11 = p[y1 * SW + x1];
    float r0  = __fadd_rn(__fmul_rn(v00, omwy), __fmul_rn(v10, wy));
    float r1  = __fadd_rn(__fmul_rn(v01, omwy), __fmul_rn(v11, wy));
    float val = __fadd_rn(__fmul_rn(r0, omwx), __fmul_rn(r1, wx));
    if (val > best) { best = val; bestc = c; }
  }
#pragma unroll
  for (int off = 1; off <= 2; off <<= 1) {
    float ov = __shfl_xor(best, off, 64);
    int   oc = __shfl_xor(bestc, off, 64);
    if (ov > best || (ov == best && oc < bestc)) { best = ov; bestc = oc; }
  }
  if (sub == 0) {
    labels[pixid] = (unsigned char)bestc;
    atomicAdd(&lcnt[bestc], 1u);           // LDS atomic (block-local)
  }
  __syncthreads();
  if (tid < NC) gcnt[blockIdx.x * NC + tid] = lcnt[tid];   // plain store
}

// ---------------------------------------------------------------------------
// Kernel 2 (hot): segment-sum as MFMA matmul, wave-private pipelines,
// NT feature loads, 2-deep register prefetch. Outputs all WRITE-ONCE:
//   sump[(hi*2+d)*19+c][f-slice]  (plain stores)
//   sq_p[block][c]                (plain stores; folded by centroid)
// ---------------------------------------------------------------------------
__global__ __launch_bounds__(256, 8) void segsum_kernel(
    const float* __restrict__ feat_s, const float* __restrict__ feat_t,
    const unsigned char* __restrict__ labels,
    float* __restrict__ sump, float* __restrict__ sq_p) {
  __shared__ unsigned short Abuf[4][2][16][64];   // 4 waves x dbuf x 2KB = 16KB

  int tid = threadIdx.x;
  int wv = tid >> 6, l = tid & 63;
  int m16 = l & 15, grp = l >> 4;
  int lrow = l >> 4;                       // sub-row 0..3 for staging
  int lpx  = (l & 15) * 4;                 // px offset 0..60 for staging

  int low = blockIdx.x & 255;
  int hi  = blockIdx.x >> 8;               // 0..7 = (ks<<1)|b
  int d = low >> 7, strip = low & 127;
  int b = hi & 1, ks = hi >> 1;

  const float* feat = d ? feat_t : feat_s;
  int px0 = ks * PXS + wv * 512;           // wave-private 512-px chunk
  const float* fbase = feat + ((size_t)(b * FDIM + strip * 16)) * NPIX + px0;
  const unsigned char* labp = labels + (d * 2 + b) * NPIX + px0;

  unsigned short (*mybuf)[16][64] = Abuf[wv];    // [2][16][64]

  f32x4 accS0 = {0.f,0.f,0.f,0.f}, accS1 = {0.f,0.f,0.f,0.f};
  f32x4 accQ0 = {0.f,0.f,0.f,0.f}, accQ1 = {0.f,0.f,0.f,0.f};

  f4v ld0[4], ld1[4];

#define LOADW(REG, W)                                                         \
  _Pragma("unroll") for (int r = 0; r < 4; ++r)                               \
    REG[r] = __builtin_nontemporal_load(                                      \
        (const f4v*)(fbase + (size_t)(r * 4 + lrow) * NPIX + (W) * 64 + lpx));

#define WRITEW(REG, CUR)                                                      \
  _Pragma("unroll") for (int r = 0; r < 4; ++r) {                             \
    int row = r * 4 + lrow;                                                   \
    unsigned u0 = ((unsigned)(unsigned short)f32_to_bf16_bits(REG[r].x)) |    \
                  (((unsigned)(unsigned short)f32_to_bf16_bits(REG[r].y)) << 16);\
    unsigned u1 = ((unsigned)(unsigned short)f32_to_bf16_bits(REG[r].z)) |    \
                  (((unsigned)(unsigned short)f32_to_bf16_bits(REG[r].w)) << 16);\
    int wbyte = (row * 128 + lpx * 2) ^ ((row & 7) << 4);                     \
    *(uint2*)((char*)&mybuf[CUR][0][0] + wbyte) = make_uint2(u0, u1);         \
  }

#define COMPW(W, CUR)                                                         \
  _Pragma("unroll") for (int t = 0; t < 2; ++t) {                             \
    int rbyte = (m16 * 128 + t * 64 + grp * 16) ^ ((m16 & 7) << 4);           \
    short8v a = *(const short8v*)((const char*)&mybuf[CUR][0][0] + rbyte);    \
    short8v a2;                                                               \
    _Pragma("unroll") for (int j = 0; j < 8; ++j) {                           \
      float x = bf16_bits_to_f32(a[j]);                                       \
      a2[j] = f32_to_bf16_bits(x * x);                                        \
    }                                                                         \
    uint2 lw = *(const uint2*)(labp + (W) * 64 + t * 32 + grp * 8);           \
    short8v b0, b1;                                                           \
    _Pragma("unroll") for (int j = 0; j < 8; ++j) {                           \
      unsigned lab = ((j < 4 ? lw.x : lw.y) >> ((j & 3) * 8)) & 0xFFu;        \
      b0[j] = (lab == (unsigned)m16)        ? (short)0x3F80 : (short)0;       \
      b1[j] = (lab == (unsigned)(m16 + 16)) ? (short)0x3F80 : (short)0;       \
    }                                                                         \
    accS0 = __builtin_amdgcn_mfma_f32_16x16x32_bf16(a,  b0, accS0, 0, 0, 0);  \
    accS1 = __builtin_amdgcn_mfma_f32_16x16x32_bf16(a,  b1, accS1, 0, 0, 0);  \
    accQ0 = __builtin_amdgcn_mfma_f32_16x16x32_bf16(a2, b0, accQ0, 0, 0, 0);  \
    accQ1 = __builtin_amdgcn_mfma_f32_16x16x32_bf16(a2, b1, accQ1, 0, 0, 0);  \
  }

  // prologue: window 0 staged; window 1 in flight (ld0)
  LOADW(ld0, 0);
  WRITEW(ld0, 0);
  LOADW(ld0, 1);

#pragma unroll
  for (int w = 0; w < 8; w += 2) {
    if (w + 2 < 8) { LOADW(ld1, w + 2); }   // issue 2 windows ahead
    COMPW(w, 0);
    if (w + 1 < 8) { WRITEW(ld0, 1); }      // wait ld0 only (ld1 stays in flight)
    if (w + 3 < 8) { LOADW(ld0, w + 3); }
    COMPW(w + 1, 1);
    if (w + 2 < 8) { WRITEW(ld1, 0); }
  }
#undef LOADW
#undef WRITEW
#undef COMPW

  // ---- epilogue: barrier (Sred aliases Abuf), merge 4 waves, plain stores
  __syncthreads();
  float* Sred = (float*)&Abuf[0][0][0][0];   // [4][19][16] = 4864 B
  float* Qred = Sred + 4 * 19 * 16;          // [4][19]

  int c0 = l & 15, frb = (l >> 4) * 4;       // C/D: col=class, row=(l>>4)*4+reg
  *(f32x4*)&Sred[(wv * 19 + c0) * 16 + frb] = accS0;
  if (c0 < 3) *(f32x4*)&Sred[(wv * 19 + 16 + c0) * 16 + frb] = accS1;

  float q0 = accQ0[0] + accQ0[1] + accQ0[2] + accQ0[3];
  float q1 = accQ1[0] + accQ1[1] + accQ1[2] + accQ1[3];
  q0 += __shfl_xor(q0, 16, 64); q0 += __shfl_xor(q0, 32, 64);
  q1 += __shfl_xor(q1, 16, 64); q1 += __shfl_xor(q1, 32, 64);
  if (l < 16) Qred[wv * 19 + l] = q0;
  if (l < 3)  Qred[wv * 19 + 16 + l] = q1;
  __syncthreads();

  // block-private slice: sump[(hi*2+d)*19+c][strip*16+fr] — written exactly once
  float* myslice = sump + ((size_t)(hi * 2 + d) * NC) * FDIM + strip * 16;
  for (int t = tid; t < NC * 16; t += 256) {
    int c = t >> 4, fr = t & 15;
    float sv = Sred[(0 * 19 + c) * 16 + fr] + Sred[(1 * 19 + c) * 16 + fr] +
               Sred[(2 * 19 + c) * 16 + fr] + Sred[(3 * 19 + c) * 16 + fr];
    myslice[(size_t)c * FDIM + fr] = sv;
  }
  if (tid < NC) {
    float qv = Qred[tid] + Qred[19 + tid] + Qred[38 + tid] + Qred[57 + tid];
    sq_p[(size_t)((hi * 2 + d) * 128 + strip) * NC + tid] = qv;  // plain store
  }
}

// Block reduction helper (256 threads)
__device__ inline float block_reduce(float v, float* red, int tid) {
  red[tid] = v; __syncthreads();
  for (int s = 128; s > 0; s >>= 1) {
    if (tid < s) red[tid] += red[tid + s];
    __syncthreads();
  }
  float r = red[0];
  __syncthreads();
  return r;
}

// ---------------------------------------------------------------------------
// Kernel 3a: 152 blocks = 19 classes x 8 f-slices. Block (c, j):
//  - folds gcnt -> cs,ct (writes cntf if j==0)
//  - folds sump over 16 partials for its 256 f (1 f per thread), writes cent
//  - partial ds,dt,cc -> dotsp[j][c][*]
//  - folds sq_p for strips [j*16, j*16+16) x 16 slices -> pqp[j][c][*]
// All plain stores, one writer per slot.
// ---------------------------------------------------------------------------
__global__ __launch_bounds__(256) void centroid_kernel(
    const float* __restrict__ sump, const float* __restrict__ sq_p,
    const unsigned int* __restrict__ gcnt,
    float* __restrict__ cent, float* __restrict__ dotsp,
    float* __restrict__ pqp, float* __restrict__ cntf) {
  __shared__ float red[256];
  int bid = blockIdx.x;
  int c = bid % NC, j = bid / NC;          // j = f-slice 0..7
  int tid = threadIdx.x;

  // fold counts: thread t: labels block t (dom0) and 256+t (dom1)
  float cs = block_reduce((float)gcnt[tid * NC + c], red, tid);
  float ct = block_reduce((float)gcnt[(256 + tid) * NC + c], red, tid);
  if (tid == 0 && j == 0) { cntf[c] = cs; cntf[NC + c] = ct; }
  float denom = fmaxf(cs + ct, 1.0f);

  // fold sump for one f per thread
  int f = j * 256 + tid;
  float ssv = 0.f, stv = 0.f;
#pragma unroll
  for (int hi = 0; hi < 8; ++hi) {
    ssv += sump[((size_t)(hi * 2 + 0) * NC + c) * FDIM + f];
    stv += sump[((size_t)(hi * 2 + 1) * NC + c) * FDIM + f];
  }
  float cf = (ssv + stv) / denom;
  cent[(size_t)c * FDIM + f] = cf;

  float rds = block_reduce(cf * ssv, red, tid);
  float rdt = block_reduce(cf * stv, red, tid);
  float rcc = block_reduce(cf * cf, red, tid);

  // fold sq_p: thread t handles (slice = t>>4, strip = j*16 + (t&15))
  int slice = tid >> 4, strip = j * 16 + (tid & 15);
  float v = sq_p[(size_t)(slice * 128 + strip) * NC + c];
  float qs = block_reduce((slice & 1) == 0 ? v : 0.f, red, tid);
  float qt = block_reduce((slice & 1) == 1 ? v : 0.f, red, tid);

  if (tid == 0) {
    dotsp[(j * NC + c) * 3 + 0] = rds;
    dotsp[(j * NC + c) * 3 + 1] = rdt;
    dotsp[(j * NC + c) * 3 + 2] = rcc;
    pqp[(j * NC + c) * 2 + 0] = qs;
    pqp[(j * NC + c) * 2 + 1] = qt;
  }
}

// ---------------------------------------------------------------------------
// Kernel 3b: row[i] = sum_{j != i, seen i&j} sum_f (c_i - c_j)^2
// ---------------------------------------------------------------------------
__global__ __launch_bounds__(256) void pair_kernel(
    const float* __restrict__ cent, const float* __restrict__ cntf,
    float* __restrict__ row) {
  __shared__ float red[256];
  int i = blockIdx.x;
  int tid = threadIdx.x;
  bool seen_i = (cntf[i] + cntf[NC + i]) > 0.f;
  float acc = 0.f;
  if (seen_i) {
    for (int j = 0; j < NC; ++j) {
      if (j == i) continue;
      if ((cntf[j] + cntf[NC + j]) <= 0.f) continue;
      for (int f = tid; f < FDIM; f += 256) {
        float dd = cent[(size_t)i * FDIM + f] - cent[(size_t)j * FDIM + f];
        acc += dd * dd;
      }
    }
  }
  float r = block_reduce(acc, red, tid);
  if (tid == 0) row[i] = r;
}

// ---------------------------------------------------------------------------
// Kernel 3c: fold slice partials, assemble the 3 outputs (p == 2).
// One wave, lane c handles class c; ballot/popc + shfl_down trees.
// ---------------------------------------------------------------------------
__global__ void final_kernel(
    const float* __restrict__ cntf, const float* __restrict__ dotsp,
    const float* __restrict__ pqp, const float* __restrict__ row,
    float* __restrict__ out) {
  int l = threadIdx.x;                      // one wave of 64
  const float fdim = (float)FDIM;
  bool isC = l < NC;
  int c = isC ? l : 0;

  float cs = 0.f, ct = 0.f, qs = 0.f, qt = 0.f;
  float d_s = 0.f, d_t = 0.f, cc = 0.f, rw = 0.f;
  if (isC) {
    cs = cntf[c]; ct = cntf[NC + c];
#pragma unroll
    for (int j = 0; j < 8; ++j) {           // independent loads, all in flight
      qs  += pqp[(j * NC + c) * 2 + 0];
      qt  += pqp[(j * NC + c) * 2 + 1];
      d_s += dotsp[(j * NC + c) * 3 + 0];
      d_t += dotsp[(j * NC + c) * 3 + 1];
      cc  += dotsp[(j * NC + c) * 3 + 2];
    }
    rw = row[c];
  }
  bool seen = isC && (cs + ct > 0.f);
  float nseenf = (float)__popcll(__ballot(seen));
  float nvs    = (float)__popcll(__ballot(isC && cs > 0.f));
  float nvt    = (float)__popcll(__ballot(isC && ct > 0.f));

  float fs = 0.f, ft = 0.f, cd = 0.f;
  if (isC && cs > 0.f) {
    float ssq = fmaxf(qs - 2.0f * d_s + cs * cc, 0.f);
    fs = sqrtf(ssq) / (cs * fdim);
  }
  if (isC && ct > 0.f) {
    float ssq = fmaxf(qt - 2.0f * d_t + ct * cc, 0.f);
    ft = sqrtf(ssq) / (ct * fdim);
  }
  if (seen) cd = sqrtf(rw) / ((nseenf - 1.0f) * fdim);

#pragma unroll
  for (int off = 32; off > 0; off >>= 1) {
    fs += __shfl_down(fs, off, 64);
    ft += __shfl_down(ft, off, 64);
    cd += __shfl_down(cd, off, 64);
  }
  if (l == 0) {
    out[0] = cd / nseenf;
    out[1] = fs / nvs;
    out[2] = ft / nvt;
  }
}

extern "C" void kernel_launch(void* const* d_in, const int* in_sizes, int n_in,
                              void* d_out, int out_size, void* d_ws, size_t ws_size,
                              hipStream_t stream) {
  const float* sfeat = (const float*)d_in[0];
  const float* ssm   = (const float*)d_in[1];
  const float* tfeat = (const float*)d_in[2];
  const float* tsm   = (const float*)d_in[3];
  float* out = (float*)d_out;

  char* ws = (char*)d_ws;
  unsigned int*  gcnt   = (unsigned int*)(ws + OFF_GCNT);
  float*         sq_p   = (float*)(ws + OFF_SQP);
  float*         sump   = (float*)(ws + OFF_SUMP);
  unsigned char* labels = (unsigned char*)(ws + OFF_LAB);
  float*         cent   = (float*)(ws + OFF_CENT);
  float*         dotsp  = (float*)(ws + OFF_DOTSP);
  float*         pqp    = (float*)(ws + OFF_PQP);
  float*         cntf   = (float*)(ws + OFF_CNTF);
  float*         row    = (float*)(ws + OFF_ROW);

  // NO memset: every buffer is written before it is read, every launch.
  labels_kernel  <<<512,    256, 0, stream>>>(ssm, tsm, labels, gcnt);
  segsum_kernel  <<<2048,   256, 0, stream>>>(sfeat, tfeat, labels, sump, sq_p);
  centroid_kernel<<<NC * 8, 256, 0, stream>>>(sump, sq_p, gcnt, cent, dotsp, pqp, cntf);
  pair_kernel    <<<NC,     256, 0, stream>>>(cent, cntf, row);
  final_kernel   <<<1,      64,  0, stream>>>(cntf, dotsp, pqp, row, out);
}

// Round 12
// 104.584 us; speedup vs baseline: 1.3472x; 1.1762x over previous
//
#include <hip/hip_runtime.h>
#include <hip/hip_bf16.h>

// Problem constants
#define BB 2
#define FDIM 2048
#define FH 64
#define FW 128
#define NPIX (FH*FW)        // 8192 pixels per (dom,b)
#define NC 19
#define SH 512
#define SW 1024

#define KS 4                // pixel splits per (d,b) plane
#define PXS (NPIX/KS)       // 2048 pixels per block (512 per wave)

// Workspace layout (bytes). EVERYTHING write-once: no memset, no atomics.
#define OFF_GCNT  0                         // uint  gcnt[1024][19]     = 77824 B
#define OFF_SQP   77824                     // float sq_p[2048][19]     = 155648 B
#define OFF_SUMP  233472                    // float sump[16][19][2048] = 2490368 B
#define OFF_LAB   2723840                   // uchar labels[2][2][8192] = 32768 B
#define OFF_CENT  2756608                   // float cent[19][2048]     = 155648 B
#define OFF_DOTSP 2912256                   // float dotsp[8][19][3]    = 1824 B
#define OFF_PQP   2914080                   // float pqp[8][19][2]      = 1216 B
#define OFF_CNTF  2915296                   // float cntf[2][19]        = 152 B
#define OFF_ROW   2915448                   // float row[19]            = 76 B

typedef __attribute__((ext_vector_type(8))) short short8v;   // 8 bf16 (4 VGPRs)
typedef __attribute__((ext_vector_type(4))) float f32x4;     // MFMA C/D
typedef __attribute__((ext_vector_type(4))) float f4v;       // NT-loadable float4

__device__ inline short f32_to_bf16_bits(float x) {
  __hip_bfloat16 h = __float2bfloat16(x);
  return *reinterpret_cast<short*>(&h);
}
__device__ inline float bf16_bits_to_f32(short s) {
  unsigned u = ((unsigned)s & 0xFFFFu) << 16;
  return __uint_as_float(u);
}

// ---------------------------------------------------------------------------
// Kernel 1: labels via align_corners bilinear downsample + argmax over C.
// 8 lanes per output pixel (<=3 channels each, 12 independent loads),
// 3-step shfl_xor argmax merge, first-max tie-break. 1024 blocks.
// Replicates jnp.linspace f32 arithmetic / mul-add association exactly.
// ---------------------------------------------------------------------------
__global__ __launch_bounds__(256) void labels_kernel(
    const float* __restrict__ sm_s, const float* __restrict__ sm_t,
    unsigned char* __restrict__ labels, unsigned int* __restrict__ gcnt) {
  __shared__ unsigned int lcnt[NC];
  int tid = threadIdx.x;
  if (tid < NC) lcnt[tid] = 0u;
  __syncthreads();

  int g = blockIdx.x * 256 + tid;          // 0..262143
  int pixid = g >> 3;                      // 0..32767
  int sub = g & 7;
  int dom = pixid >> 14;                   // block-uniform (blocks 0..511 = dom0)
  int rem = pixid & 16383;
  int b   = rem >> 13;                     // block-uniform (32 px/block)
  int pix = rem & (NPIX - 1);
  int oy  = pix >> 7;
  int ox  = pix & (FW - 1);

  const float* sm = dom ? sm_t : sm_s;

  const float step_y = 511.0f / 63.0f;
  const float step_x = 1023.0f / 127.0f;
  float fy = __fmul_rn((float)oy, step_y);
  float fx = __fmul_rn((float)ox, step_x);
  int y0 = (int)floorf(fy); int y1 = min(y0 + 1, SH - 1);
  int x0 = (int)floorf(fx); int x1 = min(x0 + 1, SW - 1);
  float wy = __fsub_rn(fy, (float)y0);
  float wx = __fsub_rn(fx, (float)x0);
  float omwy = __fsub_rn(1.0f, wy);
  float omwx = __fsub_rn(1.0f, wx);

  const float* base = sm + (size_t)b * (NC * SH * SW);
  float best = -1.0f; int bestc = 127;
  for (int c = sub; c < NC; c += 8) {
    const float* p = base + (size_t)c * (SH * SW);
    float v00 = p[y0 * SW + x0];
    float v01 = p[y0 * SW + x1];
    float v10 = p[y1 * SW + x0];
    float v11 = p[y1 * SW + x1];
    float r0  = __fadd_rn(__fmul_rn(v00, omwy), __fmul_rn(v10, wy));
    float r1  = __fadd_rn(__fmul_rn(v01, omwy), __fmul_rn(v11, wy));
    float val = __fadd_rn(__fmul_rn(r0, omwx), __fmul_rn(r1, wx));
    if (val > best) { best = val; bestc = c; }
  }
#pragma unroll
  for (int off = 1; off <= 4; off <<= 1) {
    float ov = __shfl_xor(best, off, 64);
    int   oc = __shfl_xor(bestc, off, 64);
    if (ov > best || (ov == best && oc < bestc)) { best = ov; bestc = oc; }
  }
  if (sub == 0) {
    labels[pixid] = (unsigned char)bestc;
    atomicAdd(&lcnt[bestc], 1u);           // LDS atomic (block-local)
  }
  __syncthreads();
  if (tid < NC) gcnt[blockIdx.x * NC + tid] = lcnt[tid];   // plain store
}

// ---------------------------------------------------------------------------
// Kernel 2 (hot): segment-sum as MFMA matmul, wave-private pipelines.
// R12 change: window 64->128 px; each NT load covers 2 rows x 512-B
// CONTIGUOUS half-wave segments (was 4 rows x 256 B) -- doubles the
// per-request DRAM granularity of the ~131K concurrent streams.
// Single [16][128] bf16 LDS tile per wave (16 KB/block); the ld[8]
// register prefetch is the second buffer (R10: deeper pipeline = null).
// Outputs write-once: sump slices + sq_p (plain stores, no atomics).
// ---------------------------------------------------------------------------
__global__ __launch_bounds__(256, 5) void segsum_kernel(
    const float* __restrict__ feat_s, const float* __restrict__ feat_t,
    const unsigned char* __restrict__ labels,
    float* __restrict__ sump, float* __restrict__ sq_p) {
  __shared__ unsigned short Abuf[4][16][128];   // 4 waves x 4KB = 16KB

  int tid = threadIdx.x;
  int wv = tid >> 6, l = tid & 63;
  int m16 = l & 15, grp = l >> 4;
  int lhalf = l >> 5;                      // row parity for staging
  int lpx   = (l & 31) * 4;                // px offset 0..124 for staging

  int low = blockIdx.x & 255;
  int hi  = blockIdx.x >> 8;               // 0..7 = (ks<<1)|b
  int d = low >> 7, strip = low & 127;
  int b = hi & 1, ks = hi >> 1;

  const float* feat = d ? feat_t : feat_s;
  int px0 = ks * PXS + wv * 512;           // wave-private 512-px chunk
  const float* fbase = feat + ((size_t)(b * FDIM + strip * 16)) * NPIX + px0;
  const unsigned char* labp = labels + (d * 2 + b) * NPIX + px0;

  unsigned short (*mybuf)[128] = Abuf[wv];      // [16][128]

  f32x4 accS0 = {0.f,0.f,0.f,0.f}, accS1 = {0.f,0.f,0.f,0.f};
  f32x4 accQ0 = {0.f,0.f,0.f,0.f}, accQ1 = {0.f,0.f,0.f,0.f};

  f4v ld[8];

#define LOADW(W)                                                              \
  _Pragma("unroll") for (int r = 0; r < 8; ++r)                               \
    ld[r] = __builtin_nontemporal_load(                                       \
        (const f4v*)(fbase + (size_t)(r * 2 + lhalf) * NPIX + (W) * 128 + lpx));

#define WRITEW()                                                              \
  _Pragma("unroll") for (int r = 0; r < 8; ++r) {                             \
    int row = r * 2 + lhalf;                                                  \
    unsigned u0 = ((unsigned)(unsigned short)f32_to_bf16_bits(ld[r].x)) |     \
                  (((unsigned)(unsigned short)f32_to_bf16_bits(ld[r].y)) << 16);\
    unsigned u1 = ((unsigned)(unsigned short)f32_to_bf16_bits(ld[r].z)) |     \
                  (((unsigned)(unsigned short)f32_to_bf16_bits(ld[r].w)) << 16);\
    int wbyte = (row * 256 + (l & 31) * 8) ^ ((row & 7) << 4);                \
    *(uint2*)((char*)&mybuf[0][0] + wbyte) = make_uint2(u0, u1);              \
  }

#define COMPW(W)                                                              \
  _Pragma("unroll") for (int kt = 0; kt < 4; ++kt) {                          \
    int rbyte = (m16 * 256 + kt * 64 + grp * 16) ^ ((m16 & 7) << 4);          \
    short8v a = *(const short8v*)((const char*)&mybuf[0][0] + rbyte);         \
    short8v a2;                                                               \
    _Pragma("unroll") for (int j = 0; j < 8; ++j) {                           \
      float x = bf16_bits_to_f32(a[j]);                                       \
      a2[j] = f32_to_bf16_bits(x * x);                                        \
    }                                                                         \
    uint2 lw = *(const uint2*)(labp + (W) * 128 + kt * 32 + grp * 8);         \
    short8v b0, b1;                                                           \
    _Pragma("unroll") for (int j = 0; j < 8; ++j) {                           \
      unsigned lab = ((j < 4 ? lw.x : lw.y) >> ((j & 3) * 8)) & 0xFFu;        \
      b0[j] = (lab == (unsigned)m16)        ? (short)0x3F80 : (short)0;       \
      b1[j] = (lab == (unsigned)(m16 + 16)) ? (short)0x3F80 : (short)0;       \
    }                                                                         \
    accS0 = __builtin_amdgcn_mfma_f32_16x16x32_bf16(a,  b0, accS0, 0, 0, 0);  \
    accS1 = __builtin_amdgcn_mfma_f32_16x16x32_bf16(a,  b1, accS1, 0, 0, 0);  \
    accQ0 = __builtin_amdgcn_mfma_f32_16x16x32_bf16(a2, b0, accQ0, 0, 0, 0);  \
    accQ1 = __builtin_amdgcn_mfma_f32_16x16x32_bf16(a2, b1, accQ1, 0, 0, 0);  \
  }

  // prologue: window 0
  LOADW(0);
  WRITEW();

#pragma unroll
  for (int w = 0; w < 4; ++w) {
    if (w < 3) { LOADW(w + 1); }           // issue next window's 8 loads
    COMPW(w);                              // compute current (reads mybuf)
    if (w < 3) { WRITEW(); }               // vmcnt wait covered by COMPW;
                                           // same-wave LDS order: write-after-read OK
  }
#undef LOADW
#undef WRITEW
#undef COMPW

  // ---- epilogue: barrier (Sred aliases Abuf), merge 4 waves, plain stores
  __syncthreads();
  float* Sred = (float*)&Abuf[0][0][0];      // [4][19][16] = 4864 B
  float* Qred = Sred + 4 * 19 * 16;          // [4][19]

  int c0 = l & 15, frb = (l >> 4) * 4;       // C/D: col=class, row=(l>>4)*4+reg
  *(f32x4*)&Sred[(wv * 19 + c0) * 16 + frb] = accS0;
  if (c0 < 3) *(f32x4*)&Sred[(wv * 19 + 16 + c0) * 16 + frb] = accS1;

  float q0 = accQ0[0] + accQ0[1] + accQ0[2] + accQ0[3];
  float q1 = accQ1[0] + accQ1[1] + accQ1[2] + accQ1[3];
  q0 += __shfl_xor(q0, 16, 64); q0 += __shfl_xor(q0, 32, 64);
  q1 += __shfl_xor(q1, 16, 64); q1 += __shfl_xor(q1, 32, 64);
  if (l < 16) Qred[wv * 19 + l] = q0;
  if (l < 3)  Qred[wv * 19 + 16 + l] = q1;
  __syncthreads();

  // block-private slice: sump[(hi*2+d)*19+c][strip*16+fr] — written exactly once
  float* myslice = sump + ((size_t)(hi * 2 + d) * NC) * FDIM + strip * 16;
  for (int t = tid; t < NC * 16; t += 256) {
    int c = t >> 4, fr = t & 15;
    float sv = Sred[(0 * 19 + c) * 16 + fr] + Sred[(1 * 19 + c) * 16 + fr] +
               Sred[(2 * 19 + c) * 16 + fr] + Sred[(3 * 19 + c) * 16 + fr];
    myslice[(size_t)c * FDIM + fr] = sv;
  }
  if (tid < NC) {
    float qv = Qred[tid] + Qred[19 + tid] + Qred[38 + tid] + Qred[57 + tid];
    sq_p[(size_t)((hi * 2 + d) * 128 + strip) * NC + tid] = qv;  // plain store
  }
}

// Block reduction helper (256 threads)
__device__ inline float block_reduce(float v, float* red, int tid) {
  red[tid] = v; __syncthreads();
  for (int s = 128; s > 0; s >>= 1) {
    if (tid < s) red[tid] += red[tid + s];
    __syncthreads();
  }
  float r = red[0];
  __syncthreads();
  return r;
}

// ---------------------------------------------------------------------------
// Kernel 3a: 152 blocks = 19 classes x 8 f-slices. Block (c, j):
//  - folds gcnt -> cs,ct (writes cntf if j==0)
//  - folds sump over 16 partials for its 256 f (1 f per thread), writes cent
//  - partial ds,dt,cc -> dotsp[j][c][*]
//  - folds sq_p for strips [j*16, j*16+16) x 16 slices -> pqp[j][c][*]
// All plain stores, one writer per slot.
// ---------------------------------------------------------------------------
__global__ __launch_bounds__(256) void centroid_kernel(
    const float* __restrict__ sump, const float* __restrict__ sq_p,
    const unsigned int* __restrict__ gcnt,
    float* __restrict__ cent, float* __restrict__ dotsp,
    float* __restrict__ pqp, float* __restrict__ cntf) {
  __shared__ float red[256];
  int bid = blockIdx.x;
  int c = bid % NC, j = bid / NC;          // j = f-slice 0..7
  int tid = threadIdx.x;

  // fold counts: 1024 label blocks; 0..511 dom0, 512..1023 dom1
  float csp = (float)gcnt[tid * NC + c] + (float)gcnt[(256 + tid) * NC + c];
  float ctp = (float)gcnt[(512 + tid) * NC + c] + (float)gcnt[(768 + tid) * NC + c];
  float cs = block_reduce(csp, red, tid);
  float ct = block_reduce(ctp, red, tid);
  if (tid == 0 && j == 0) { cntf[c] = cs; cntf[NC + c] = ct; }
  float denom = fmaxf(cs + ct, 1.0f);

  // fold sump for one f per thread
  int f = j * 256 + tid;
  float ssv = 0.f, stv = 0.f;
#pragma unroll
  for (int hi = 0; hi < 8; ++hi) {
    ssv += sump[((size_t)(hi * 2 + 0) * NC + c) * FDIM + f];
    stv += sump[((size_t)(hi * 2 + 1) * NC + c) * FDIM + f];
  }
  float cf = (ssv + stv) / denom;
  cent[(size_t)c * FDIM + f] = cf;

  float rds = block_reduce(cf * ssv, red, tid);
  float rdt = block_reduce(cf * stv, red, tid);
  float rcc = block_reduce(cf * cf, red, tid);

  // fold sq_p: thread t handles (slice = t>>4, strip = j*16 + (t&15))
  int slice = tid >> 4, strip = j * 16 + (tid & 15);
  float v = sq_p[(size_t)(slice * 128 + strip) * NC + c];
  float qs = block_reduce((slice & 1) == 0 ? v : 0.f, red, tid);
  float qt = block_reduce((slice & 1) == 1 ? v : 0.f, red, tid);

  if (tid == 0) {
    dotsp[(j * NC + c) * 3 + 0] = rds;
    dotsp[(j * NC + c) * 3 + 1] = rdt;
    dotsp[(j * NC + c) * 3 + 2] = rcc;
    pqp[(j * NC + c) * 2 + 0] = qs;
    pqp[(j * NC + c) * 2 + 1] = qt;
  }
}

// ---------------------------------------------------------------------------
// Kernel 3b: row[i] = sum_{j != i, seen i&j} sum_f (c_i - c_j)^2
// ---------------------------------------------------------------------------
__global__ __launch_bounds__(256) void pair_kernel(
    const float* __restrict__ cent, const float* __restrict__ cntf,
    float* __restrict__ row) {
  __shared__ float red[256];
  int i = blockIdx.x;
  int tid = threadIdx.x;
  bool seen_i = (cntf[i] + cntf[NC + i]) > 0.f;
  float acc = 0.f;
  if (seen_i) {
    for (int j = 0; j < NC; ++j) {
      if (j == i) continue;
      if ((cntf[j] + cntf[NC + j]) <= 0.f) continue;
      for (int f = tid; f < FDIM; f += 256) {
        float dd = cent[(size_t)i * FDIM + f] - cent[(size_t)j * FDIM + f];
        acc += dd * dd;
      }
    }
  }
  float r = block_reduce(acc, red, tid);
  if (tid == 0) row[i] = r;
}

// ---------------------------------------------------------------------------
// Kernel 3c: fold slice partials, assemble the 3 outputs (p == 2).
// One wave, lane c handles class c; ballot/popc + shfl_down trees.
// ---------------------------------------------------------------------------
__global__ void final_kernel(
    const float* __restrict__ cntf, const float* __restrict__ dotsp,
    const float* __restrict__ pqp, const float* __restrict__ row,
    float* __restrict__ out) {
  int l = threadIdx.x;                      // one wave of 64
  const float fdim = (float)FDIM;
  bool isC = l < NC;
  int c = isC ? l : 0;

  float cs = 0.f, ct = 0.f, qs = 0.f, qt = 0.f;
  float d_s = 0.f, d_t = 0.f, cc = 0.f, rw = 0.f;
  if (isC) {
    cs = cntf[c]; ct = cntf[NC + c];
#pragma unroll
    for (int j = 0; j < 8; ++j) {           // independent loads, all in flight
      qs  += pqp[(j * NC + c) * 2 + 0];
      qt  += pqp[(j * NC + c) * 2 + 1];
      d_s += dotsp[(j * NC + c) * 3 + 0];
      d_t += dotsp[(j * NC + c) * 3 + 1];
      cc  += dotsp[(j * NC + c) * 3 + 2];
    }
    rw = row[c];
  }
  bool seen = isC && (cs + ct > 0.f);
  float nseenf = (float)__popcll(__ballot(seen));
  float nvs    = (float)__popcll(__ballot(isC && cs > 0.f));
  float nvt    = (float)__popcll(__ballot(isC && ct > 0.f));

  float fs = 0.f, ft = 0.f, cd = 0.f;
  if (isC && cs > 0.f) {
    float ssq = fmaxf(qs - 2.0f * d_s + cs * cc, 0.f);
    fs = sqrtf(ssq) / (cs * fdim);
  }
  if (isC && ct > 0.f) {
    float ssq = fmaxf(qt - 2.0f * d_t + ct * cc, 0.f);
    ft = sqrtf(ssq) / (ct * fdim);
  }
  if (seen) cd = sqrtf(rw) / ((nseenf - 1.0f) * fdim);

#pragma unroll
  for (int off = 32; off > 0; off >>= 1) {
    fs += __shfl_down(fs, off, 64);
    ft += __shfl_down(ft, off, 64);
    cd += __shfl_down(cd, off, 64);
  }
  if (l == 0) {
    out[0] = cd / nseenf;
    out[1] = fs / nvs;
    out[2] = ft / nvt;
  }
}

extern "C" void kernel_launch(void* const* d_in, const int* in_sizes, int n_in,
                              void* d_out, int out_size, void* d_ws, size_t ws_size,
                              hipStream_t stream) {
  const float* sfeat = (const float*)d_in[0];
  const float* ssm   = (const float*)d_in[1];
  const float* tfeat = (const float*)d_in[2];
  const float* tsm   = (const float*)d_in[3];
  float* out = (float*)d_out;

  char* ws = (char*)d_ws;
  unsigned int*  gcnt   = (unsigned int*)(ws + OFF_GCNT);
  float*         sq_p   = (float*)(ws + OFF_SQP);
  float*         sump   = (float*)(ws + OFF_SUMP);
  unsigned char* labels = (unsigned char*)(ws + OFF_LAB);
  float*         cent   = (float*)(ws + OFF_CENT);
  float*         dotsp  = (float*)(ws + OFF_DOTSP);
  float*         pqp    = (float*)(ws + OFF_PQP);
  float*         cntf   = (float*)(ws + OFF_CNTF);
  float*         row    = (float*)(ws + OFF_ROW);

  // NO memset: every buffer is written before it is read, every launch.
  labels_kernel  <<<1024,   256, 0, stream>>>(ssm, tsm, labels, gcnt);
  segsum_kernel  <<<2048,   256, 0, stream>>>(sfeat, tfeat, labels, sump, sq_p);
  centroid_kernel<<<NC * 8, 256, 0, stream>>>(sump, sq_p, gcnt, cent, dotsp, pqp, cntf);
  pair_kernel    <<<NC,     256, 0, stream>>>(cent, cntf, row);
  final_kernel   <<<1,      64,  0, stream>>>(cntf, dotsp, pqp, row, out);
}